// Round 3
// baseline (824.235 us; speedup 1.0000x reference)
//
#include <hip/hip_runtime.h>
#include <hip/hip_bf16.h>

#define NODES 50000
#define NEDGE 800000
#define ETOT  850000   /* NEDGE + NODES self loops */

typedef __hip_bfloat16 bf16;

__device__ __forceinline__ float bf2f(bf16 v) { return __bfloat162float(v); }
__device__ __forceinline__ bf16 f2bf(float v) { return __float2bfloat16(v); }

// dtype-generic load/store
__device__ __forceinline__ float ldf(const float* p, int i) { return p[i]; }
__device__ __forceinline__ float ldf(const bf16* p, int i) { return bf2f(p[i]); }
__device__ __forceinline__ void stf(float* p, int i, float v) { p[i] = v; }
__device__ __forceinline__ void stf(bf16* p, int i, float v) { p[i] = f2bf(v); }

// ---------------------------------------------------------------------------
// k_detect: ln_gamma is exactly ones. fp32 one = 0x3F800000; packed bf16 ones
// = 0x3F803F80. flag: 0 = fp32, 1 = bf16.
// ---------------------------------------------------------------------------
__global__ void k_detect(const unsigned int* gamma_bits, int* flag) {
    if (threadIdx.x == 0)
        flag[0] = (gamma_bits[0] == 0x3F800000u) ? 0 : 1;
}

// ---------------------------------------------------------------------------
// k_prep: histogram of dst (incl. self loops) + sum of edge_attr (for mean)
// ---------------------------------------------------------------------------
template <typename T, int TAG>
__global__ __launch_bounds__(256) void k_prep(const int* flag, const T* edge_attr,
                                              const int* ei, float* sum_ea, int* count) {
    if (flag[0] != TAG) return;
    int tid = blockIdx.x * blockDim.x + threadIdx.x;
    int stride = gridDim.x * blockDim.x;
    float local = 0.f;
    for (int e = tid; e < ETOT; e += stride) {
        int dst = (e < NEDGE) ? ei[NEDGE + e] : (e - NEDGE);
        atomicAdd(&count[dst], 1);
        if (e < NEDGE) local += ldf(edge_attr, e);
    }
    #pragma unroll
    for (int s = 1; s < 64; s <<= 1) local += __shfl_xor(local, s, 64);
    if ((threadIdx.x & 63) == 0) atomicAdd(sum_ea, local);
}

// ---------------------------------------------------------------------------
// k_xform: xl = x@W_l + b_l ; xr = x@W_r + b_r   (staged bf16 always)
// ---------------------------------------------------------------------------
template <typename T, int TAG>
__global__ __launch_bounds__(256) void k_xform(const int* flag, const T* x,
                                               const T* W_l, const T* b_l,
                                               const T* W_r, const T* b_r,
                                               bf16* xl, bf16* xr) {
    if (flag[0] != TAG) return;
    __shared__ __align__(16) float s_x[32][132];
    const int tid = threadIdx.x;
    const int n0 = blockIdx.x * 32;
    for (int it = 0; it < 16; ++it) {
        int idx = it * 256 + tid;
        int n = idx >> 7, j = idx & 127;
        int node = n0 + n;
        s_x[n][j] = (node < NODES) ? ldf(x, node * 128 + j) : 0.f;
    }
    __syncthreads();
    const T* W = (tid < 128) ? W_l : W_r;
    const T* bb = (tid < 128) ? b_l : b_r;
    bf16* dstp = (tid < 128) ? xl : xr;
    const int col = tid & 127;
    float acc[32];
    #pragma unroll
    for (int n = 0; n < 32; ++n) acc[n] = 0.f;
    for (int k = 0; k < 128; k += 4) {
        float w0 = ldf(W, (k + 0) * 128 + col);
        float w1 = ldf(W, (k + 1) * 128 + col);
        float w2 = ldf(W, (k + 2) * 128 + col);
        float w3 = ldf(W, (k + 3) * 128 + col);
        #pragma unroll
        for (int n = 0; n < 32; ++n) {
            const float4 xv = *(const float4*)&s_x[n][k];
            acc[n] += xv.x * w0 + xv.y * w1 + xv.z * w2 + xv.w * w3;
        }
    }
    float bias = ldf(bb, col);
    for (int n = 0; n < 32; ++n) {
        int node = n0 + n;
        if (node < NODES) dstp[node * 128 + col] = f2bf(acc[n] + bias);
    }
}

// ---------------------------------------------------------------------------
// k_scan: exclusive prefix sum of count -> off, also init cursor = off
// ---------------------------------------------------------------------------
__global__ __launch_bounds__(1024) void k_scan(const int* count, int* off, int* cursor) {
    __shared__ int s[1024];
    const int t = threadIdx.x;
    const int CHUNK = (NODES + 1023) / 1024;  // 49
    int lo = t * CHUNK;
    int hi = lo + CHUNK; if (hi > NODES) hi = NODES; if (lo > NODES) lo = NODES;
    int sum = 0;
    for (int i = lo; i < hi; ++i) sum += count[i];
    s[t] = sum;
    __syncthreads();
    for (int st = 1; st < 1024; st <<= 1) {
        int v = 0;
        if (t >= st) v = s[t - st];
        __syncthreads();
        if (t >= st) s[t] += v;
        __syncthreads();
    }
    int run = (t == 0) ? 0 : s[t - 1];
    for (int i = lo; i < hi; ++i) {
        off[i] = run; cursor[i] = run; run += count[i];
    }
    if (t == 1023) off[NODES] = s[1023];
}

// ---------------------------------------------------------------------------
// k_place: perm[pos] = edge id, grouped by dst
// ---------------------------------------------------------------------------
__global__ __launch_bounds__(256) void k_place(const int* ei, int* cursor, int* perm) {
    int tid = blockIdx.x * blockDim.x + threadIdx.x;
    int stride = gridDim.x * blockDim.x;
    for (int e = tid; e < ETOT; e += stride) {
        int dst = (e < NEDGE) ? ei[NEDGE + e] : (e - NEDGE);
        int pos = atomicAdd(&cursor[dst], 1);
        perm[pos] = e;
    }
}

// ---------------------------------------------------------------------------
// k_agg: one wave per node; per-edge GATv2 logit on the fly (4-shfl head
// reduction over 16-lane groups), online softmax, accumulate alpha*xl[src].
// Lane owns channels c=2*lane, 2*lane+1 (same head h=lane>>4).
// ---------------------------------------------------------------------------
template <typename T, int TAG>
__global__ __launch_bounds__(256) void k_agg(const int* flag,
                                             const unsigned int* xl32,
                                             const unsigned int* xr32,
                                             const T* edge_attr, const int* ei,
                                             const int* off, const int* perm,
                                             const T* W_e, const T* att,
                                             const float* sum_ea, T* out_agg) {
    if (flag[0] != TAG) return;
    const int lane = threadIdx.x & 63;
    const int wid = threadIdx.x >> 6;
    const int wave0 = blockIdx.x * 4 + wid;
    const int nwaves = gridDim.x * 4;
    const int c = 2 * lane;
    const float we1 = ldf(W_e, c), we2 = ldf(W_e, c + 1);
    const float a1 = ldf(att, c), a2 = ldf(att, c + 1);
    const float meanv = sum_ea[0] * (1.f / (float)NEDGE);
    for (int n = wave0; n < NODES; n += nwaves) {
        unsigned int xru = xr32[n * 64 + lane];
        float xr1 = __uint_as_float((xru & 0xffffu) << 16);
        float xr2 = __uint_as_float(xru & 0xffff0000u);
        int s0 = off[n], s1 = off[n + 1];
        float m = -1e30f, l = 0.f, acc1 = 0.f, acc2 = 0.f;
        for (int j = s0; j < s1; ++j) {
            int pe = perm[j];
            int src; float eav;
            if (pe < NEDGE) { src = ei[pe]; eav = ldf(edge_attr, pe); }
            else            { src = pe - NEDGE; eav = meanv; }
            unsigned int xu = xl32[src * 64 + lane];
            float xj1 = __uint_as_float((xu & 0xffffu) << 16);
            float xj2 = __uint_as_float(xu & 0xffff0000u);
            float m1 = xj1 + xr1 + eav * we1;
            float m2 = xj2 + xr2 + eav * we2;
            m1 = (m1 > 0.f) ? m1 : 0.2f * m1;
            m2 = (m2 > 0.f) ? m2 : 0.2f * m2;
            float p = m1 * a1 + m2 * a2;
            p += __shfl_xor(p, 1, 64);
            p += __shfl_xor(p, 2, 64);
            p += __shfl_xor(p, 4, 64);
            p += __shfl_xor(p, 8, 64);
            float nm = fmaxf(m, p);
            float sc = __expf(m - nm);
            float ee = __expf(p - nm);
            l = l * sc + ee;
            acc1 = acc1 * sc + ee * xj1;
            acc2 = acc2 * sc + ee * xj2;
            m = nm;
        }
        float inv = 1.f / fmaxf(l, 1e-30f);
        stf(out_agg, n * 128 + c, acc1 * inv);
        stf(out_agg, n * 128 + c + 1, acc2 * inv);
    }
}

// ---------------------------------------------------------------------------
// k_epi: per 32-node tile: h=elu(out+bias); gate=sigmoid(h@Wg+bg);
// y=g*h+(1-g)*x; t=relu(y@W1+b1); y+=t@W2+b2; LayerNorm -> out
// out_agg aliases out (d_out): tile fully read into LDS before final write.
// ---------------------------------------------------------------------------
template <typename T, int TAG>
__global__ __launch_bounds__(256) void k_epi(const int* flag, const T* out_agg,
                                             const T* x, const T* bias_out,
                                             const T* W_gate, const T* b_gate,
                                             const T* W_ffn1, const T* b_ffn1,
                                             const T* W_ffn2, const T* b_ffn2,
                                             const T* gamma, const T* beta,
                                             T* out) {
    if (flag[0] != TAG) return;
    __shared__ __align__(16) float s_h[32][132];
    __shared__ __align__(16) float s_t[32][260];
    __shared__ float s_g[32];
    __shared__ float s_mu[32], s_rs[32];
    const int tid = threadIdx.x;
    const int n0 = blockIdx.x * 32;
    int nn = NODES - n0; if (nn > 32) nn = 32;

    // phase 1: h = elu(out_agg + bias_out)
    for (int it = 0; it < 16; ++it) {
        int idx = it * 256 + tid;
        int n = idx >> 7, j = idx & 127;
        float v = 0.f;
        if (n < nn) {
            v = ldf(out_agg, (n0 + n) * 128 + j) + ldf(bias_out, j);
            v = (v > 0.f) ? v : (__expf(v) - 1.f);
        }
        s_h[n][j] = v;
    }
    __syncthreads();
    // gate
    if (tid < 32) {
        float g = 0.f;
        if (tid < nn) {
            for (int k = 0; k < 128; ++k) g += s_h[tid][k] * ldf(W_gate, k);
            g += ldf(b_gate, 0);
        }
        s_g[tid] = 1.f / (1.f + __expf(-g));
    }
    __syncthreads();
    // y = g*h + (1-g)*x   (in place into s_h)
    for (int it = 0; it < 16; ++it) {
        int idx = it * 256 + tid;
        int n = idx >> 7, j = idx & 127;
        if (n < nn) {
            float g = s_g[n];
            s_h[n][j] = g * s_h[n][j] + (1.f - g) * ldf(x, (n0 + n) * 128 + j);
        }
    }
    __syncthreads();
    // FFN1: t = relu(y @ W1 + b1); thread = output column j in [0,256)
    {
        float acc[32];
        #pragma unroll
        for (int n = 0; n < 32; ++n) acc[n] = 0.f;
        for (int k = 0; k < 128; k += 4) {
            float w0 = ldf(W_ffn1, (k + 0) * 256 + tid);
            float w1 = ldf(W_ffn1, (k + 1) * 256 + tid);
            float w2 = ldf(W_ffn1, (k + 2) * 256 + tid);
            float w3 = ldf(W_ffn1, (k + 3) * 256 + tid);
            #pragma unroll
            for (int n = 0; n < 32; ++n) {
                const float4 yv = *(const float4*)&s_h[n][k];
                acc[n] += yv.x * w0 + yv.y * w1 + yv.z * w2 + yv.w * w3;
            }
        }
        float b1 = ldf(b_ffn1, tid);
        for (int n = 0; n < 32; ++n) {
            float v = acc[n] + b1;
            s_t[n][tid] = (v > 0.f) ? v : 0.f;
        }
    }
    __syncthreads();
    // FFN2: f = t @ W2 + b2 ; yfin = y + f (in place into s_h)
    {
        const int j = tid & 127;
        const int nbase = (tid >> 7) * 16;
        float acc[16];
        #pragma unroll
        for (int n = 0; n < 16; ++n) acc[n] = 0.f;
        for (int k = 0; k < 256; k += 4) {
            float w0 = ldf(W_ffn2, (k + 0) * 128 + j);
            float w1 = ldf(W_ffn2, (k + 1) * 128 + j);
            float w2 = ldf(W_ffn2, (k + 2) * 128 + j);
            float w3 = ldf(W_ffn2, (k + 3) * 128 + j);
            #pragma unroll
            for (int n = 0; n < 16; ++n) {
                const float4 tv = *(const float4*)&s_t[nbase + n][k];
                acc[n] += tv.x * w0 + tv.y * w1 + tv.z * w2 + tv.w * w3;
            }
        }
        float b2 = ldf(b_ffn2, j);
        for (int n = 0; n < 16; ++n) {
            int nm = nbase + n;
            s_h[nm][j] = s_h[nm][j] + acc[n] + b2;
        }
    }
    __syncthreads();
    // LayerNorm stats
    if (tid < 32) {
        float s = 0.f, ss = 0.f;
        for (int k = 0; k < 128; k += 4) {
            const float4 v = *(const float4*)&s_h[tid][k];
            s  += v.x + v.y + v.z + v.w;
            ss += v.x * v.x + v.y * v.y + v.z * v.z + v.w * v.w;
        }
        float mu = s * (1.f / 128.f);
        float var = ss * (1.f / 128.f) - mu * mu;
        s_mu[tid] = mu;
        s_rs[tid] = rsqrtf(fmaxf(var, 0.f) + 1e-5f);
    }
    __syncthreads();
    for (int it = 0; it < 16; ++it) {
        int idx = it * 256 + tid;
        int n = idx >> 7, j = idx & 127;
        if (n < nn) {
            float v = (s_h[n][j] - s_mu[n]) * s_rs[n] * ldf(gamma, j) + ldf(beta, j);
            stf(out, (n0 + n) * 128 + j, v);
        }
    }
}

// ---------------------------------------------------------------------------
extern "C" void kernel_launch(void* const* d_in, const int* in_sizes, int n_in,
                              void* d_out, int out_size, void* d_ws, size_t ws_size,
                              hipStream_t stream) {
    const int* edge_index = (const int*)d_in[17];

    char* base = (char*)d_ws;
    // workspace layout (bytes), 16-aligned; total ~29.6 MB
    int*   flag    = (int*)  (base + 0);                      // 16
    float* sum_ea  = (float*)(base + 16);                     // 16
    int*   count   = (int*)  (base + 32);                     // 200000
    int*   off     = (int*)  (base + 200032);                 // 200004 (+pad)
    int*   cursor  = (int*)  (base + 400064);                 // 200000
    int*   perm    = (int*)  (base + 600064);                 // 3400000
    bf16*  xl      = (bf16*) (base + 4000064);                // 12800000
    bf16*  xr      = (bf16*) (base + 16800064);               // 12800000

    hipMemsetAsync(sum_ea, 0, 16, stream);
    hipMemsetAsync(count, 0, NODES * sizeof(int), stream);

    const int NTILES = (NODES + 31) / 32;  // 1563

    k_detect<<<1, 64, 0, stream>>>((const unsigned int*)d_in[15], flag);

    // fp32 instantiations (TAG 0)
    {
        const float* x = (const float*)d_in[0];
        const float* ea = (const float*)d_in[1];
        k_prep<float, 0><<<1024, 256, 0, stream>>>(flag, ea, edge_index, sum_ea, count);
        k_xform<float, 0><<<NTILES, 256, 0, stream>>>(flag, x,
            (const float*)d_in[2], (const float*)d_in[3],
            (const float*)d_in[4], (const float*)d_in[5], xl, xr);
    }
    // bf16 instantiations (TAG 1)
    {
        const bf16* x = (const bf16*)d_in[0];
        const bf16* ea = (const bf16*)d_in[1];
        k_prep<bf16, 1><<<1024, 256, 0, stream>>>(flag, ea, edge_index, sum_ea, count);
        k_xform<bf16, 1><<<NTILES, 256, 0, stream>>>(flag, x,
            (const bf16*)d_in[2], (const bf16*)d_in[3],
            (const bf16*)d_in[4], (const bf16*)d_in[5], xl, xr);
    }

    k_scan <<<1, 1024, 0, stream>>>(count, off, cursor);
    k_place<<<1024, 256, 0, stream>>>(edge_index, cursor, perm);

    k_agg<float, 0><<<3125, 256, 0, stream>>>(flag, (const unsigned int*)xl,
        (const unsigned int*)xr, (const float*)d_in[1], edge_index, off, perm,
        (const float*)d_in[6], (const float*)d_in[7], sum_ea, (float*)d_out);
    k_agg<bf16, 1><<<3125, 256, 0, stream>>>(flag, (const unsigned int*)xl,
        (const unsigned int*)xr, (const bf16*)d_in[1], edge_index, off, perm,
        (const bf16*)d_in[6], (const bf16*)d_in[7], sum_ea, (bf16*)d_out);

    k_epi<float, 0><<<NTILES, 256, 0, stream>>>(flag, (const float*)d_out,
        (const float*)d_in[0], (const float*)d_in[8],
        (const float*)d_in[9], (const float*)d_in[10],
        (const float*)d_in[11], (const float*)d_in[12],
        (const float*)d_in[13], (const float*)d_in[14],
        (const float*)d_in[15], (const float*)d_in[16], (float*)d_out);
    k_epi<bf16, 1><<<NTILES, 256, 0, stream>>>(flag, (const bf16*)d_out,
        (const bf16*)d_in[0], (const bf16*)d_in[8],
        (const bf16*)d_in[9], (const bf16*)d_in[10],
        (const bf16*)d_in[11], (const bf16*)d_in[12],
        (const bf16*)d_in[13], (const bf16*)d_in[14],
        (const bf16*)d_in[15], (const bf16*)d_in[16], (bf16*)d_out);
}

// Round 10
// 698.120 us; speedup vs baseline: 1.1806x; 1.1806x over previous
//
#include <hip/hip_runtime.h>
#include <hip/hip_bf16.h>

#define NODES 50000
#define NEDGE 800000
#define ETOT  850000   /* NEDGE + NODES self loops */

typedef __hip_bfloat16 bf16;

__device__ __forceinline__ bf16 f2bf(float v) { return __float2bfloat16(v); }
__device__ __forceinline__ float bflo(unsigned int v) { return __uint_as_float(v << 16); }
__device__ __forceinline__ float bfhi(unsigned int v) { return __uint_as_float(v & 0xffff0000u); }

__device__ __forceinline__ unsigned int pack2(float a, float b) {
    bf16 x = f2bf(a), y = f2bf(b);
    unsigned short xs = *reinterpret_cast<unsigned short*>(&x);
    unsigned short ys = *reinterpret_cast<unsigned short*>(&y);
    return ((unsigned int)ys << 16) | (unsigned int)xs;
}

// ---------------------------------------------------------------------------
// k_prep: histogram of dst (incl. self loops) + sum of edge_attr (for mean)
// ---------------------------------------------------------------------------
__global__ __launch_bounds__(256) void k_prep(const float* edge_attr, const int* ei,
                                              float* sum_ea, int* count) {
    int tid = blockIdx.x * blockDim.x + threadIdx.x;
    int stride = gridDim.x * blockDim.x;
    float local = 0.f;
    for (int e = tid; e < ETOT; e += stride) {
        int dst = (e < NEDGE) ? ei[NEDGE + e] : (e - NEDGE);
        atomicAdd(&count[dst], 1);
        if (e < NEDGE) local += edge_attr[e];
    }
    #pragma unroll
    for (int s = 1; s < 64; s <<= 1) local += __shfl_xor(local, s, 64);
    if ((threadIdx.x & 63) == 0) atomicAdd(sum_ea, local);
}

// ---------------------------------------------------------------------------
// k_xform: xl = x@W_l + b_l ; xr = x@W_r + b_r  (fp32 in, bf16-packed out)
// 32 nodes/block. W is [k][128] fp32, col-contiguous -> thread owns 4 cols
// (one float4 per k) x 8 nodes (LDS broadcasts).
//   mat = tid>>7, ng = (tid>>5)&3, cg = tid&31.
// ---------------------------------------------------------------------------
__global__ __launch_bounds__(256) void k_xform(const float* x,
                                               const float* W_l, const float* b_l,
                                               const float* W_r, const float* b_r,
                                               bf16* xl, bf16* xr) {
    __shared__ __align__(16) float s_x[32][132];
    const int tid = threadIdx.x;
    const int n0 = blockIdx.x * 32;
    // load x tile: 4096 floats = 4 float4 per thread
    for (int it = 0; it < 4; ++it) {
        int idx4 = (it * 256 + tid) * 4;
        int n = idx4 >> 7, j = idx4 & 127;
        int node = n0 + n;
        float4 v = make_float4(0.f, 0.f, 0.f, 0.f);
        if (node < NODES) v = *(const float4*)(x + node * 128 + j);
        *(float4*)&s_x[n][j] = v;
    }
    __syncthreads();
    const int mat = tid >> 7;
    const int ng  = (tid >> 5) & 3;
    const int cg  = tid & 31;
    const float* W  = mat ? W_r : W_l;
    const float* bb = mat ? b_r : b_l;
    bf16* dst = mat ? xr : xl;
    const int c0 = cg * 4, nb = ng * 8;
    float acc[4][8];
    #pragma unroll
    for (int c = 0; c < 4; ++c)
        #pragma unroll
        for (int n = 0; n < 8; ++n) acc[c][n] = 0.f;
    for (int k = 0; k < 128; ++k) {
        float4 w = *(const float4*)(W + k * 128 + c0);
        #pragma unroll
        for (int n = 0; n < 8; ++n) {
            float xv = s_x[nb + n][k];
            acc[0][n] += xv * w.x;
            acc[1][n] += xv * w.y;
            acc[2][n] += xv * w.z;
            acc[3][n] += xv * w.w;
        }
    }
    float4 bv = *(const float4*)(bb + c0);
    for (int n = 0; n < 8; ++n) {
        int node = n0 + nb + n;
        if (node < NODES) {
            uint2 u;
            u.x = pack2(acc[0][n] + bv.x, acc[1][n] + bv.y);
            u.y = pack2(acc[2][n] + bv.z, acc[3][n] + bv.w);
            *(uint2*)(dst + node * 128 + c0) = u;
        }
    }
}

// ---------------------------------------------------------------------------
// k_scan: exclusive prefix sum of count -> off, init cursor = off.
// [byte-identical to round-3 proven version: SEPARATE buffers]
// ---------------------------------------------------------------------------
__global__ __launch_bounds__(1024) void k_scan(const int* count, int* off, int* cursor) {
    __shared__ int s[1024];
    const int t = threadIdx.x;
    const int CHUNK = (NODES + 1023) / 1024;  // 49
    int lo = t * CHUNK;
    int hi = lo + CHUNK; if (hi > NODES) hi = NODES; if (lo > NODES) lo = NODES;
    int sum = 0;
    for (int i = lo; i < hi; ++i) sum += count[i];
    s[t] = sum;
    __syncthreads();
    for (int st = 1; st < 1024; st <<= 1) {
        int v = 0;
        if (t >= st) v = s[t - st];
        __syncthreads();
        if (t >= st) s[t] += v;
        __syncthreads();
    }
    int run = (t == 0) ? 0 : s[t - 1];
    for (int i = lo; i < hi; ++i) {
        off[i] = run; cursor[i] = run; run += count[i];
    }
    if (t == 1023) off[NODES] = s[1023];
}

// ---------------------------------------------------------------------------
// k_place: perm[pos] = edge id, grouped by dst. [round-3 proven version]
// ---------------------------------------------------------------------------
__global__ __launch_bounds__(256) void k_place(const int* ei, int* cursor, int* perm) {
    int tid = blockIdx.x * blockDim.x + threadIdx.x;
    int stride = gridDim.x * blockDim.x;
    for (int e = tid; e < ETOT; e += stride) {
        int dst = (e < NEDGE) ? ei[NEDGE + e] : (e - NEDGE);
        int pos = atomicAdd(&cursor[dst], 1);
        perm[pos] = e;
    }
}

// ---------------------------------------------------------------------------
// k_agg: one wave per node; per-edge GATv2 logit on the fly (4-shfl head
// reduction over 16-lane groups), online softmax, accumulate alpha*xl[src].
// Lane owns channels c=2*lane, 2*lane+1 (head h=lane>>4). fp32 out (d_out).
// ---------------------------------------------------------------------------
__global__ __launch_bounds__(256) void k_agg(const unsigned int* xl32,
                                             const unsigned int* xr32,
                                             const float* edge_attr, const int* ei,
                                             const int* off, const int* perm,
                                             const float* W_e, const float* att,
                                             const float* sum_ea, float* outp) {
    const int lane = threadIdx.x & 63;
    const int wave0 = blockIdx.x * 4 + (threadIdx.x >> 6);
    const int nwaves = gridDim.x * 4;
    const int c = 2 * lane;
    const float we1 = W_e[c], we2 = W_e[c + 1];
    const float a1 = att[c], a2 = att[c + 1];
    const float meanv = sum_ea[0] * (1.f / (float)NEDGE);
    for (int n = wave0; n < NODES; n += nwaves) {
        unsigned int xru = xr32[n * 64 + lane];
        float xr1 = bflo(xru), xr2 = bfhi(xru);
        int s0 = off[n], s1 = off[n + 1];
        float m = -1e30f, l = 0.f, acc1 = 0.f, acc2 = 0.f;
        for (int j = s0; j < s1; ++j) {
            int pe = perm[j];
            int src; float eav;
            if (pe < NEDGE) { src = ei[pe]; eav = edge_attr[pe]; }
            else            { src = pe - NEDGE; eav = meanv; }
            unsigned int xu = xl32[src * 64 + lane];
            float xj1 = bflo(xu), xj2 = bfhi(xu);
            float m1 = xj1 + xr1 + eav * we1;
            float m2 = xj2 + xr2 + eav * we2;
            m1 = (m1 > 0.f) ? m1 : 0.2f * m1;
            m2 = (m2 > 0.f) ? m2 : 0.2f * m2;
            float p = m1 * a1 + m2 * a2;
            p += __shfl_xor(p, 1, 64);
            p += __shfl_xor(p, 2, 64);
            p += __shfl_xor(p, 4, 64);
            p += __shfl_xor(p, 8, 64);
            float nm = fmaxf(m, p);
            float sc = __expf(m - nm);
            float ee = __expf(p - nm);
            l = l * sc + ee;
            acc1 = acc1 * sc + ee * xj1;
            acc2 = acc2 * sc + ee * xj2;
            m = nm;
        }
        float inv = 1.f / fmaxf(l, 1e-30f);
        *(float2*)(outp + n * 128 + c) = make_float2(acc1 * inv, acc2 * inv);
    }
}

// ---------------------------------------------------------------------------
// k_epi (fp32, register-blocked, direct weight layout):
// h=elu(out+bias); gate=sigmoid(h@Wg+bg); y=g*h+(1-g)*x;
// t=relu(y@W1+b1); y+=t@W2+b2; LayerNorm -> fp32 out.
// FFN1: thread owns 4 cols (float4 W1 row slice) x 8 nodes (LDS broadcast).
// FFN2: thread owns 4 cols x 4 nodes.
// out_agg aliases out (d_out): tile fully read into LDS before final write.
// ---------------------------------------------------------------------------
__global__ __launch_bounds__(256) void k_epi(const float* out_agg, const float* x,
                                             const float* bias_out,
                                             const float* W_gate, const float* b_gate,
                                             const float* W1, const float* b_ffn1,
                                             const float* W2, const float* b_ffn2,
                                             const float* gamma, const float* beta,
                                             float* out) {
    __shared__ __align__(16) float s_h[32][132];
    __shared__ __align__(16) float s_t[32][260];
    __shared__ float s_g[32];
    __shared__ float s_mu[32], s_rs[32];
    const int tid = threadIdx.x;
    const int n0 = blockIdx.x * 32;
    int nn = NODES - n0; if (nn > 32) nn = 32;

    // phase 1: h = elu(out_agg + bias_out)
    for (int it = 0; it < 4; ++it) {
        int idx4 = (it * 256 + tid) * 4;
        int n = idx4 >> 7, j = idx4 & 127;
        float4 w = make_float4(0.f, 0.f, 0.f, 0.f);
        if (n < nn) {
            float4 v  = *(const float4*)(out_agg + (n0 + n) * 128 + j);
            float4 bv = *(const float4*)(bias_out + j);
            float t0 = v.x + bv.x, t1 = v.y + bv.y;
            float t2 = v.z + bv.z, t3 = v.w + bv.w;
            w.x = (t0 > 0.f) ? t0 : (__expf(t0) - 1.f);
            w.y = (t1 > 0.f) ? t1 : (__expf(t1) - 1.f);
            w.z = (t2 > 0.f) ? t2 : (__expf(t2) - 1.f);
            w.w = (t3 > 0.f) ? t3 : (__expf(t3) - 1.f);
        }
        *(float4*)&s_h[n][j] = w;
    }
    __syncthreads();
    // gate
    if (tid < 32) {
        float g = 0.f;
        for (int k = 0; k < 128; k += 4) {
            float4 w = *(const float4*)(W_gate + k);
            float4 h = *(const float4*)&s_h[tid][k];
            g += h.x * w.x + h.y * w.y + h.z * w.z + h.w * w.w;
        }
        g += b_gate[0];
        s_g[tid] = 1.f / (1.f + __expf(-g));
    }
    __syncthreads();
    // y = g*h + (1-g)*x   (in place into s_h)
    for (int it = 0; it < 4; ++it) {
        int idx4 = (it * 256 + tid) * 4;
        int n = idx4 >> 7, j = idx4 & 127;
        if (n < nn) {
            float g = s_g[n];
            float4 xv = *(const float4*)(x + (n0 + n) * 128 + j);
            float4 h = *(float4*)&s_h[n][j];
            h.x = g * h.x + (1.f - g) * xv.x;
            h.y = g * h.y + (1.f - g) * xv.y;
            h.z = g * h.z + (1.f - g) * xv.z;
            h.w = g * h.w + (1.f - g) * xv.w;
            *(float4*)&s_h[n][j] = h;
        }
    }
    __syncthreads();
    // FFN1: t = relu(y @ W1 + b1). cg = tid&63 -> cols c0..c0+3; ng = tid>>6
    // -> nodes nb..nb+7.  W1 is [k][256] fp32, col contiguous -> float4 per k.
    {
        const int cg = tid & 63, ng = tid >> 6;
        const int c0 = cg * 4, nb = ng * 8;
        float acc[4][8];
        #pragma unroll
        for (int cc = 0; cc < 4; ++cc)
            #pragma unroll
            for (int n = 0; n < 8; ++n) acc[cc][n] = 0.f;
        for (int k = 0; k < 128; ++k) {
            float4 w = *(const float4*)(W1 + k * 256 + c0);
            #pragma unroll
            for (int n = 0; n < 8; ++n) {
                float yv = s_h[nb + n][k];
                acc[0][n] += yv * w.x;
                acc[1][n] += yv * w.y;
                acc[2][n] += yv * w.z;
                acc[3][n] += yv * w.w;
            }
        }
        float4 bv = *(const float4*)(b_ffn1 + c0);
        for (int n = 0; n < 8; ++n) {
            float4 v;
            v.x = fmaxf(acc[0][n] + bv.x, 0.f);
            v.y = fmaxf(acc[1][n] + bv.y, 0.f);
            v.z = fmaxf(acc[2][n] + bv.z, 0.f);
            v.w = fmaxf(acc[3][n] + bv.w, 0.f);
            *(float4*)&s_t[nb + n][c0] = v;
        }
    }
    __syncthreads();
    // FFN2: y += t @ W2 + b2. cg = tid&31 -> cols j0..j0+3; ng = tid>>5
    // -> nodes nb..nb+3.  W2 is [k][128] fp32, col contiguous -> float4 per k.
    {
        const int cg = tid & 31, ng = tid >> 5;
        const int j0 = cg * 4, nb = ng * 4;
        float acc[4][4];
        #pragma unroll
        for (int cc = 0; cc < 4; ++cc)
            #pragma unroll
            for (int n = 0; n < 4; ++n) acc[cc][n] = 0.f;
        for (int k = 0; k < 256; ++k) {
            float4 w = *(const float4*)(W2 + k * 128 + j0);
            #pragma unroll
            for (int n = 0; n < 4; ++n) {
                float tv = s_t[nb + n][k];
                acc[0][n] += tv * w.x;
                acc[1][n] += tv * w.y;
                acc[2][n] += tv * w.z;
                acc[3][n] += tv * w.w;
            }
        }
        float4 bv = *(const float4*)(b_ffn2 + j0);
        for (int n = 0; n < 4; ++n) {
            float4 h = *(float4*)&s_h[nb + n][j0];
            h.x += acc[0][n] + bv.x;
            h.y += acc[1][n] + bv.y;
            h.z += acc[2][n] + bv.z;
            h.w += acc[3][n] + bv.w;
            *(float4*)&s_h[nb + n][j0] = h;
        }
    }
    __syncthreads();
    // LayerNorm stats
    if (tid < 32) {
        float s = 0.f, ss = 0.f;
        for (int k = 0; k < 128; k += 4) {
            const float4 v = *(const float4*)&s_h[tid][k];
            s  += v.x + v.y + v.z + v.w;
            ss += v.x * v.x + v.y * v.y + v.z * v.z + v.w * v.w;
        }
        float mu = s * (1.f / 128.f);
        float var = ss * (1.f / 128.f) - mu * mu;
        s_mu[tid] = mu;
        s_rs[tid] = rsqrtf(fmaxf(var, 0.f) + 1e-5f);
    }
    __syncthreads();
    // normalize + store (fp32)
    for (int it = 0; it < 4; ++it) {
        int idx4 = (it * 256 + tid) * 4;
        int n = idx4 >> 7, j = idx4 & 127;
        if (n < nn) {
            float mu = s_mu[n], rs = s_rs[n];
            float4 gv = *(const float4*)(gamma + j);
            float4 bv = *(const float4*)(beta + j);
            float4 v = *(const float4*)&s_h[n][j];
            float4 o;
            o.x = (v.x - mu) * rs * gv.x + bv.x;
            o.y = (v.y - mu) * rs * gv.y + bv.y;
            o.z = (v.z - mu) * rs * gv.z + bv.z;
            o.w = (v.w - mu) * rs * gv.w + bv.w;
            *(float4*)(out + (n0 + n) * 128 + j) = o;
        }
    }
}

// ---------------------------------------------------------------------------
extern "C" void kernel_launch(void* const* d_in, const int* in_sizes, int n_in,
                              void* d_out, int out_size, void* d_ws, size_t ws_size,
                              hipStream_t stream) {
    const float* x         = (const float*)d_in[0];
    const float* edge_attr = (const float*)d_in[1];
    const int* edge_index  = (const int*)d_in[17];
    float* out = (float*)d_out;

    char* base = (char*)d_ws;
    // workspace layout: EXACTLY the round-3 hardware-proven layout
    // (total 29,600,064 B; first 16 B unused).
    float* sum_ea  = (float*)(base + 16);                     // 16
    int*   count   = (int*)  (base + 32);                     // 200000
    int*   off     = (int*)  (base + 200032);                 // 200004 (+pad)
    int*   cursor  = (int*)  (base + 400064);                 // 200000
    int*   perm    = (int*)  (base + 600064);                 // 3400000
    bf16*  xl      = (bf16*) (base + 4000064);                // 12800000
    bf16*  xr      = (bf16*) (base + 16800064);               // 12800000

    hipMemsetAsync(sum_ea, 0, 16, stream);
    hipMemsetAsync(count, 0, NODES * sizeof(int), stream);

    const int NTILES = (NODES + 31) / 32;  // 1563

    k_prep  <<<1024, 256, 0, stream>>>(edge_attr, edge_index, sum_ea, count);
    k_xform <<<NTILES, 256, 0, stream>>>(x, (const float*)d_in[2], (const float*)d_in[3],
                                         (const float*)d_in[4], (const float*)d_in[5],
                                         xl, xr);
    k_scan  <<<1, 1024, 0, stream>>>(count, off, cursor);
    k_place <<<1024, 256, 0, stream>>>(edge_index, cursor, perm);
    k_agg   <<<3125, 256, 0, stream>>>((const unsigned int*)xl,
                                       (const unsigned int*)xr,
                                       edge_attr, edge_index, off, perm,
                                       (const float*)d_in[6], (const float*)d_in[7],
                                       sum_ea, out);
    k_epi   <<<NTILES, 256, 0, stream>>>(out, x, (const float*)d_in[8],
                                         (const float*)d_in[9], (const float*)d_in[10],
                                         (const float*)d_in[11], (const float*)d_in[12],
                                         (const float*)d_in[13], (const float*)d_in[14],
                                         (const float*)d_in[15], (const float*)d_in[16],
                                         out);
}

// Round 11
// 583.508 us; speedup vs baseline: 1.4126x; 1.1964x over previous
//
#include <hip/hip_runtime.h>
#include <hip/hip_bf16.h>

#define NODES 50000
#define NEDGE 800000
#define ETOT  850000   /* NEDGE + NODES self loops */

typedef __hip_bfloat16 bf16;

__device__ __forceinline__ bf16 f2bf(float v) { return __float2bfloat16(v); }
__device__ __forceinline__ float bflo(unsigned int v) { return __uint_as_float(v << 16); }
__device__ __forceinline__ float bfhi(unsigned int v) { return __uint_as_float(v & 0xffff0000u); }

__device__ __forceinline__ unsigned int pack2(float a, float b) {
    bf16 x = f2bf(a), y = f2bf(b);
    unsigned short xs = *reinterpret_cast<unsigned short*>(&x);
    unsigned short ys = *reinterpret_cast<unsigned short*>(&y);
    return ((unsigned int)ys << 16) | (unsigned int)xs;
}

__device__ __forceinline__ unsigned short bfbits(float v) {
    bf16 x = f2bf(v);
    return *reinterpret_cast<unsigned short*>(&x);
}

// ---------------------------------------------------------------------------
// k_prep: histogram of dst (incl. self loops) + sum of edge_attr (for mean)
// [byte-identical to passing R10]
// ---------------------------------------------------------------------------
__global__ __launch_bounds__(256) void k_prep(const float* edge_attr, const int* ei,
                                              float* sum_ea, int* count) {
    int tid = blockIdx.x * blockDim.x + threadIdx.x;
    int stride = gridDim.x * blockDim.x;
    float local = 0.f;
    for (int e = tid; e < ETOT; e += stride) {
        int dst = (e < NEDGE) ? ei[NEDGE + e] : (e - NEDGE);
        atomicAdd(&count[dst], 1);
        if (e < NEDGE) local += edge_attr[e];
    }
    #pragma unroll
    for (int s = 1; s < 64; s <<= 1) local += __shfl_xor(local, s, 64);
    if ((threadIdx.x & 63) == 0) atomicAdd(sum_ea, local);
}

// ---------------------------------------------------------------------------
// k_xform: xl = x@W_l + b_l ; xr = x@W_r + b_r  [byte-identical to passing R10]
// ---------------------------------------------------------------------------
__global__ __launch_bounds__(256) void k_xform(const float* x,
                                               const float* W_l, const float* b_l,
                                               const float* W_r, const float* b_r,
                                               bf16* xl, bf16* xr) {
    __shared__ __align__(16) float s_x[32][132];
    const int tid = threadIdx.x;
    const int n0 = blockIdx.x * 32;
    for (int it = 0; it < 4; ++it) {
        int idx4 = (it * 256 + tid) * 4;
        int n = idx4 >> 7, j = idx4 & 127;
        int node = n0 + n;
        float4 v = make_float4(0.f, 0.f, 0.f, 0.f);
        if (node < NODES) v = *(const float4*)(x + node * 128 + j);
        *(float4*)&s_x[n][j] = v;
    }
    __syncthreads();
    const int mat = tid >> 7;
    const int ng  = (tid >> 5) & 3;
    const int cg  = tid & 31;
    const float* W  = mat ? W_r : W_l;
    const float* bb = mat ? b_r : b_l;
    bf16* dst = mat ? xr : xl;
    const int c0 = cg * 4, nb = ng * 8;
    float acc[4][8];
    #pragma unroll
    for (int c = 0; c < 4; ++c)
        #pragma unroll
        for (int n = 0; n < 8; ++n) acc[c][n] = 0.f;
    for (int k = 0; k < 128; ++k) {
        float4 w = *(const float4*)(W + k * 128 + c0);
        #pragma unroll
        for (int n = 0; n < 8; ++n) {
            float xv = s_x[nb + n][k];
            acc[0][n] += xv * w.x;
            acc[1][n] += xv * w.y;
            acc[2][n] += xv * w.z;
            acc[3][n] += xv * w.w;
        }
    }
    float4 bv = *(const float4*)(bb + c0);
    for (int n = 0; n < 8; ++n) {
        int node = n0 + nb + n;
        if (node < NODES) {
            uint2 u;
            u.x = pack2(acc[0][n] + bv.x, acc[1][n] + bv.y);
            u.y = pack2(acc[2][n] + bv.z, acc[3][n] + bv.w);
            *(uint2*)(dst + node * 128 + c0) = u;
        }
    }
}

// ---------------------------------------------------------------------------
// k_scan: exclusive prefix sum of count -> off, init cursor = off.
// [byte-identical to passing R10]
// ---------------------------------------------------------------------------
__global__ __launch_bounds__(1024) void k_scan(const int* count, int* off, int* cursor) {
    __shared__ int s[1024];
    const int t = threadIdx.x;
    const int CHUNK = (NODES + 1023) / 1024;  // 49
    int lo = t * CHUNK;
    int hi = lo + CHUNK; if (hi > NODES) hi = NODES; if (lo > NODES) lo = NODES;
    int sum = 0;
    for (int i = lo; i < hi; ++i) sum += count[i];
    s[t] = sum;
    __syncthreads();
    for (int st = 1; st < 1024; st <<= 1) {
        int v = 0;
        if (t >= st) v = s[t - st];
        __syncthreads();
        if (t >= st) s[t] += v;
        __syncthreads();
    }
    int run = (t == 0) ? 0 : s[t - 1];
    for (int i = lo; i < hi; ++i) {
        off[i] = run; cursor[i] = run; run += count[i];
    }
    if (t == 1023) off[NODES] = s[1023];
}

// ---------------------------------------------------------------------------
// k_place: perm[pos] = (ea_bf16_bits << 16) | src, grouped by dst.
// src < 65536 (NODES = 50000). Removes two dependent random reads per edge
// from k_agg's inner loop. Workspace entry stays 4 bytes.
// ---------------------------------------------------------------------------
__global__ __launch_bounds__(256) void k_place(const int* ei, const float* edge_attr,
                                               const float* sum_ea,
                                               int* cursor, unsigned int* perm) {
    const float meanv = sum_ea[0] * (1.f / (float)NEDGE);
    int tid = blockIdx.x * blockDim.x + threadIdx.x;
    int stride = gridDim.x * blockDim.x;
    for (int e = tid; e < ETOT; e += stride) {
        int src, dst; float eav;
        if (e < NEDGE) { src = ei[e]; dst = ei[NEDGE + e]; eav = edge_attr[e]; }
        else           { src = e - NEDGE; dst = src; eav = meanv; }
        int pos = atomicAdd(&cursor[dst], 1);
        perm[pos] = ((unsigned int)bfbits(eav) << 16) | (unsigned int)src;
    }
}

// ---------------------------------------------------------------------------
// k_agg: one wave per node; 4-edge unrolled online softmax. All 4 perm words
// + 4 xl row-gathers issue before any compute (4x memory-level parallelism);
// the four shfl head-reductions interleave; one combined softmax update.
// Lane owns channels c=2*lane, 2*lane+1 (head h=lane>>4). fp32 out (d_out).
// ---------------------------------------------------------------------------
__global__ __launch_bounds__(256) void k_agg(const unsigned int* xl32,
                                             const unsigned int* xr32,
                                             const unsigned int* perm, const int* off,
                                             const float* W_e, const float* att,
                                             float* outp) {
    const int lane = threadIdx.x & 63;
    const int wave0 = blockIdx.x * 4 + (threadIdx.x >> 6);
    const int nwaves = gridDim.x * 4;
    const int c = 2 * lane;
    const float we1 = W_e[c], we2 = W_e[c + 1];
    const float a1 = att[c], a2 = att[c + 1];
    for (int n = wave0; n < NODES; n += nwaves) {
        unsigned int xru = xr32[n * 64 + lane];
        float xr1 = bflo(xru), xr2 = bfhi(xru);
        int s0 = off[n], s1 = off[n + 1];
        float m = -1e30f, l = 0.f, acc1 = 0.f, acc2 = 0.f;
        int j = s0;
        for (; j + 4 <= s1; j += 4) {
            unsigned int u0 = perm[j];
            unsigned int u1 = perm[j + 1];
            unsigned int u2 = perm[j + 2];
            unsigned int u3 = perm[j + 3];
            unsigned int g0 = xl32[(u0 & 0xffffu) * 64 + lane];
            unsigned int g1 = xl32[(u1 & 0xffffu) * 64 + lane];
            unsigned int g2 = xl32[(u2 & 0xffffu) * 64 + lane];
            unsigned int g3 = xl32[(u3 & 0xffffu) * 64 + lane];
            float e0 = bfhi(u0), e1 = bfhi(u1), e2 = bfhi(u2), e3 = bfhi(u3);
            float x01 = bflo(g0), x02 = bfhi(g0);
            float x11 = bflo(g1), x12 = bfhi(g1);
            float x21 = bflo(g2), x22 = bfhi(g2);
            float x31 = bflo(g3), x32 = bfhi(g3);
            float p0, p1, p2, p3;
            {
                float v1 = x01 + xr1 + e0 * we1, v2 = x02 + xr2 + e0 * we2;
                v1 = (v1 > 0.f) ? v1 : 0.2f * v1;
                v2 = (v2 > 0.f) ? v2 : 0.2f * v2;
                p0 = v1 * a1 + v2 * a2;
            }
            {
                float v1 = x11 + xr1 + e1 * we1, v2 = x12 + xr2 + e1 * we2;
                v1 = (v1 > 0.f) ? v1 : 0.2f * v1;
                v2 = (v2 > 0.f) ? v2 : 0.2f * v2;
                p1 = v1 * a1 + v2 * a2;
            }
            {
                float v1 = x21 + xr1 + e2 * we1, v2 = x22 + xr2 + e2 * we2;
                v1 = (v1 > 0.f) ? v1 : 0.2f * v1;
                v2 = (v2 > 0.f) ? v2 : 0.2f * v2;
                p2 = v1 * a1 + v2 * a2;
            }
            {
                float v1 = x31 + xr1 + e3 * we1, v2 = x32 + xr2 + e3 * we2;
                v1 = (v1 > 0.f) ? v1 : 0.2f * v1;
                v2 = (v2 > 0.f) ? v2 : 0.2f * v2;
                p3 = v1 * a1 + v2 * a2;
            }
            p0 += __shfl_xor(p0, 1, 64); p1 += __shfl_xor(p1, 1, 64);
            p2 += __shfl_xor(p2, 1, 64); p3 += __shfl_xor(p3, 1, 64);
            p0 += __shfl_xor(p0, 2, 64); p1 += __shfl_xor(p1, 2, 64);
            p2 += __shfl_xor(p2, 2, 64); p3 += __shfl_xor(p3, 2, 64);
            p0 += __shfl_xor(p0, 4, 64); p1 += __shfl_xor(p1, 4, 64);
            p2 += __shfl_xor(p2, 4, 64); p3 += __shfl_xor(p3, 4, 64);
            p0 += __shfl_xor(p0, 8, 64); p1 += __shfl_xor(p1, 8, 64);
            p2 += __shfl_xor(p2, 8, 64); p3 += __shfl_xor(p3, 8, 64);
            float nm = fmaxf(fmaxf(m, fmaxf(p0, p1)), fmaxf(p2, p3));
            float sc = __expf(m - nm);
            float E0 = __expf(p0 - nm);
            float E1 = __expf(p1 - nm);
            float E2 = __expf(p2 - nm);
            float E3 = __expf(p3 - nm);
            l = l * sc + E0 + E1 + E2 + E3;
            acc1 = acc1 * sc + E0 * x01 + E1 * x11 + E2 * x21 + E3 * x31;
            acc2 = acc2 * sc + E0 * x02 + E1 * x12 + E2 * x22 + E3 * x32;
            m = nm;
        }
        for (; j < s1; ++j) {
            unsigned int u0 = perm[j];
            unsigned int g0 = xl32[(u0 & 0xffffu) * 64 + lane];
            float e0 = bfhi(u0);
            float x01 = bflo(g0), x02 = bfhi(g0);
            float v1 = x01 + xr1 + e0 * we1, v2 = x02 + xr2 + e0 * we2;
            v1 = (v1 > 0.f) ? v1 : 0.2f * v1;
            v2 = (v2 > 0.f) ? v2 : 0.2f * v2;
            float p = v1 * a1 + v2 * a2;
            p += __shfl_xor(p, 1, 64);
            p += __shfl_xor(p, 2, 64);
            p += __shfl_xor(p, 4, 64);
            p += __shfl_xor(p, 8, 64);
            float nm = fmaxf(m, p);
            float sc = __expf(m - nm);
            float ee = __expf(p - nm);
            l = l * sc + ee;
            acc1 = acc1 * sc + ee * x01;
            acc2 = acc2 * sc + ee * x02;
            m = nm;
        }
        float inv = 1.f / fmaxf(l, 1e-30f);
        *(float2*)(outp + n * 128 + c) = make_float2(acc1 * inv, acc2 * inv);
    }
}

// ---------------------------------------------------------------------------
// k_epi: [byte-identical to passing R10]
// ---------------------------------------------------------------------------
__global__ __launch_bounds__(256) void k_epi(const float* out_agg, const float* x,
                                             const float* bias_out,
                                             const float* W_gate, const float* b_gate,
                                             const float* W1, const float* b_ffn1,
                                             const float* W2, const float* b_ffn2,
                                             const float* gamma, const float* beta,
                                             float* out) {
    __shared__ __align__(16) float s_h[32][132];
    __shared__ __align__(16) float s_t[32][260];
    __shared__ float s_g[32];
    __shared__ float s_mu[32], s_rs[32];
    const int tid = threadIdx.x;
    const int n0 = blockIdx.x * 32;
    int nn = NODES - n0; if (nn > 32) nn = 32;

    // phase 1: h = elu(out_agg + bias_out)
    for (int it = 0; it < 4; ++it) {
        int idx4 = (it * 256 + tid) * 4;
        int n = idx4 >> 7, j = idx4 & 127;
        float4 w = make_float4(0.f, 0.f, 0.f, 0.f);
        if (n < nn) {
            float4 v  = *(const float4*)(out_agg + (n0 + n) * 128 + j);
            float4 bv = *(const float4*)(bias_out + j);
            float t0 = v.x + bv.x, t1 = v.y + bv.y;
            float t2 = v.z + bv.z, t3 = v.w + bv.w;
            w.x = (t0 > 0.f) ? t0 : (__expf(t0) - 1.f);
            w.y = (t1 > 0.f) ? t1 : (__expf(t1) - 1.f);
            w.z = (t2 > 0.f) ? t2 : (__expf(t2) - 1.f);
            w.w = (t3 > 0.f) ? t3 : (__expf(t3) - 1.f);
        }
        *(float4*)&s_h[n][j] = w;
    }
    __syncthreads();
    // gate
    if (tid < 32) {
        float g = 0.f;
        for (int k = 0; k < 128; k += 4) {
            float4 w = *(const float4*)(W_gate + k);
            float4 h = *(const float4*)&s_h[tid][k];
            g += h.x * w.x + h.y * w.y + h.z * w.z + h.w * w.w;
        }
        g += b_gate[0];
        s_g[tid] = 1.f / (1.f + __expf(-g));
    }
    __syncthreads();
    // y = g*h + (1-g)*x   (in place into s_h)
    for (int it = 0; it < 4; ++it) {
        int idx4 = (it * 256 + tid) * 4;
        int n = idx4 >> 7, j = idx4 & 127;
        if (n < nn) {
            float g = s_g[n];
            float4 xv = *(const float4*)(x + (n0 + n) * 128 + j);
            float4 h = *(float4*)&s_h[n][j];
            h.x = g * h.x + (1.f - g) * xv.x;
            h.y = g * h.y + (1.f - g) * xv.y;
            h.z = g * h.z + (1.f - g) * xv.z;
            h.w = g * h.w + (1.f - g) * xv.w;
            *(float4*)&s_h[n][j] = h;
        }
    }
    __syncthreads();
    // FFN1: t = relu(y @ W1 + b1). cg = tid&63 -> cols c0..c0+3; ng = tid>>6
    {
        const int cg = tid & 63, ng = tid >> 6;
        const int c0 = cg * 4, nb = ng * 8;
        float acc[4][8];
        #pragma unroll
        for (int cc = 0; cc < 4; ++cc)
            #pragma unroll
            for (int n = 0; n < 8; ++n) acc[cc][n] = 0.f;
        for (int k = 0; k < 128; ++k) {
            float4 w = *(const float4*)(W1 + k * 256 + c0);
            #pragma unroll
            for (int n = 0; n < 8; ++n) {
                float yv = s_h[nb + n][k];
                acc[0][n] += yv * w.x;
                acc[1][n] += yv * w.y;
                acc[2][n] += yv * w.z;
                acc[3][n] += yv * w.w;
            }
        }
        float4 bv = *(const float4*)(b_ffn1 + c0);
        for (int n = 0; n < 8; ++n) {
            float4 v;
            v.x = fmaxf(acc[0][n] + bv.x, 0.f);
            v.y = fmaxf(acc[1][n] + bv.y, 0.f);
            v.z = fmaxf(acc[2][n] + bv.z, 0.f);
            v.w = fmaxf(acc[3][n] + bv.w, 0.f);
            *(float4*)&s_t[nb + n][c0] = v;
        }
    }
    __syncthreads();
    // FFN2: y += t @ W2 + b2. cg = tid&31 -> cols j0..j0+3; ng = tid>>5
    {
        const int cg = tid & 31, ng = tid >> 5;
        const int j0 = cg * 4, nb = ng * 4;
        float acc[4][4];
        #pragma unroll
        for (int cc = 0; cc < 4; ++cc)
            #pragma unroll
            for (int n = 0; n < 4; ++n) acc[cc][n] = 0.f;
        for (int k = 0; k < 256; ++k) {
            float4 w = *(const float4*)(W2 + k * 128 + j0);
            #pragma unroll
            for (int n = 0; n < 4; ++n) {
                float tv = s_t[nb + n][k];
                acc[0][n] += tv * w.x;
                acc[1][n] += tv * w.y;
                acc[2][n] += tv * w.z;
                acc[3][n] += tv * w.w;
            }
        }
        float4 bv = *(const float4*)(b_ffn2 + j0);
        for (int n = 0; n < 4; ++n) {
            float4 h = *(float4*)&s_h[nb + n][j0];
            h.x += acc[0][n] + bv.x;
            h.y += acc[1][n] + bv.y;
            h.z += acc[2][n] + bv.z;
            h.w += acc[3][n] + bv.w;
            *(float4*)&s_h[nb + n][j0] = h;
        }
    }
    __syncthreads();
    // LayerNorm stats
    if (tid < 32) {
        float s = 0.f, ss = 0.f;
        for (int k = 0; k < 128; k += 4) {
            const float4 v = *(const float4*)&s_h[tid][k];
            s  += v.x + v.y + v.z + v.w;
            ss += v.x * v.x + v.y * v.y + v.z * v.z + v.w * v.w;
        }
        float mu = s * (1.f / 128.f);
        float var = ss * (1.f / 128.f) - mu * mu;
        s_mu[tid] = mu;
        s_rs[tid] = rsqrtf(fmaxf(var, 0.f) + 1e-5f);
    }
    __syncthreads();
    // normalize + store (fp32)
    for (int it = 0; it < 4; ++it) {
        int idx4 = (it * 256 + tid) * 4;
        int n = idx4 >> 7, j = idx4 & 127;
        if (n < nn) {
            float mu = s_mu[n], rs = s_rs[n];
            float4 gv = *(const float4*)(gamma + j);
            float4 bv = *(const float4*)(beta + j);
            float4 v = *(const float4*)&s_h[n][j];
            float4 o;
            o.x = (v.x - mu) * rs * gv.x + bv.x;
            o.y = (v.y - mu) * rs * gv.y + bv.y;
            o.z = (v.z - mu) * rs * gv.z + bv.z;
            o.w = (v.w - mu) * rs * gv.w + bv.w;
            *(float4*)(out + (n0 + n) * 128 + j) = o;
        }
    }
}

// ---------------------------------------------------------------------------
extern "C" void kernel_launch(void* const* d_in, const int* in_sizes, int n_in,
                              void* d_out, int out_size, void* d_ws, size_t ws_size,
                              hipStream_t stream) {
    const float* x         = (const float*)d_in[0];
    const float* edge_attr = (const float*)d_in[1];
    const int* edge_index  = (const int*)d_in[17];
    float* out = (float*)d_out;

    char* base = (char*)d_ws;
    // workspace layout: EXACTLY the hardware-proven layout (29,600,064 B).
    float* sum_ea  = (float*)(base + 16);                     // 16
    int*   count   = (int*)  (base + 32);                     // 200000
    int*   off     = (int*)  (base + 200032);                 // 200004 (+pad)
    int*   cursor  = (int*)  (base + 400064);                 // 200000
    unsigned int* perm = (unsigned int*)(base + 600064);      // 3400000
    bf16*  xl      = (bf16*) (base + 4000064);                // 12800000
    bf16*  xr      = (bf16*) (base + 16800064);               // 12800000

    hipMemsetAsync(sum_ea, 0, 16, stream);
    hipMemsetAsync(count, 0, NODES * sizeof(int), stream);

    const int NTILES = (NODES + 31) / 32;  // 1563

    k_prep  <<<1024, 256, 0, stream>>>(edge_attr, edge_index, sum_ea, count);
    k_xform <<<NTILES, 256, 0, stream>>>(x, (const float*)d_in[2], (const float*)d_in[3],
                                         (const float*)d_in[4], (const float*)d_in[5],
                                         xl, xr);
    k_scan  <<<1, 1024, 0, stream>>>(count, off, cursor);
    k_place <<<1024, 256, 0, stream>>>(edge_index, edge_attr, sum_ea, cursor, perm);
    k_agg   <<<3125, 256, 0, stream>>>((const unsigned int*)xl,
                                       (const unsigned int*)xr,
                                       perm, off,
                                       (const float*)d_in[6], (const float*)d_in[7],
                                       out);
    k_epi   <<<NTILES, 256, 0, stream>>>(out, x, (const float*)d_in[8],
                                         (const float*)d_in[9], (const float*)d_in[10],
                                         (const float*)d_in[11], (const float*)d_in[12],
                                         (const float*)d_in[13], (const float*)d_in[14],
                                         (const float*)d_in[15], (const float*)d_in[16],
                                         out);
}